// Round 2
// baseline (1034.313 us; speedup 1.0000x reference)
//
#include <hip/hip_runtime.h>

#define FANOUT 10

// ---------------- aggregation: agg[t] = mean_{j<10} xin[src[10t+j]] ----------------
// LPT lanes per target, each lane owns one float4 column chunk. Row reads are
// contiguous 512B (din=128) or 1KB (din=256) segments -> fully coalesced.
template<int DIN>
__global__ __launch_bounds__(256) void agg_kernel(const float* __restrict__ xin,
                                                  const int* __restrict__ src,
                                                  float* __restrict__ agg, int n_tgt) {
    constexpr int LPT = DIN / 4;      // lanes per target (32 or 64)
    constexpr int TPB = 256 / LPT;    // targets per block
    const int tid = threadIdx.x;
    const int t = blockIdx.x * TPB + tid / LPT;
    const int c = (tid % LPT) * 4;
    if (t >= n_tgt) return;
    const int* s = src + (size_t)t * FANOUT;
    float4 acc = make_float4(0.f, 0.f, 0.f, 0.f);
#pragma unroll
    for (int j = 0; j < FANOUT; ++j) {
        const int r = s[j];
        const float4 v = *reinterpret_cast<const float4*>(xin + (size_t)r * DIN + c);
        acc.x += v.x; acc.y += v.y; acc.z += v.z; acc.w += v.w;
    }
    const float inv = 1.0f / (float)FANOUT;
    acc.x *= inv; acc.y *= inv; acc.z *= inv; acc.w *= inv;
    *reinterpret_cast<float4*>(agg + (size_t)t * DIN + c) = acc;
}

// ---------------- fused dual GEMM: out = agg*Wl^T + xt*Wr^T + b (opt relu) ----------------
// A (M x DIN) row-major, W (BN x DIN) row-major (BN == dout, full N in one block).
// LDS tiles stored K-major with +4 padding: keeps every float4 row access
// 16B-aligned (stride stays a multiple of 4 floats). kk is wave-uniform in the
// compute reads, so row stride never affects bank mapping there.
template<int BM, int BN, int BK, int DIN, bool RELU>
__global__ __launch_bounds__(256) void sage_gemm(
        const float* __restrict__ agg, const float* __restrict__ xt,
        const float* __restrict__ Wl, const float* __restrict__ Wr,
        const float* __restrict__ bias, float* __restrict__ out, int M) {
    constexpr int TM = BM / 16;       // rows (targets) per thread
    constexpr int TN = BN / 16;       // cols (outs) per thread, processed as float4 quads
    constexpr int NQ = TN / 4;        // number of float4 quads per thread

    __shared__ float As[BK][BM + 4];
    __shared__ float Bs[BK][BN + 4];

    const int tid = threadIdx.x;
    const int tm = tid / 16;          // 0..15
    const int tn = tid % 16;          // 0..15
    const int m0 = blockIdx.x * BM;

    float acc[TM][TN];
#pragma unroll
    for (int i = 0; i < TM; ++i)
#pragma unroll
        for (int j = 0; j < TN; ++j) acc[i][j] = 0.f;

#pragma unroll
    for (int pass = 0; pass < 2; ++pass) {
        const float* __restrict__ A = pass ? xt : agg;
        const float* __restrict__ B = pass ? Wr : Wl;
        for (int k0 = 0; k0 < DIN; k0 += BK) {
            __syncthreads();
            // stage A tile (BM x BK) transposed -> As[k][row]
            for (int idx = tid * 4; idx < BM * BK; idx += 256 * 4) {
                const int row = idx / BK, kk = idx % BK;
                const float4 v = *reinterpret_cast<const float4*>(
                    A + (size_t)(m0 + row) * DIN + k0 + kk);
                As[kk + 0][row] = v.x; As[kk + 1][row] = v.y;
                As[kk + 2][row] = v.z; As[kk + 3][row] = v.w;
            }
            // stage B tile (BN x BK) transposed -> Bs[k][o]
            for (int idx = tid * 4; idx < BN * BK; idx += 256 * 4) {
                const int row = idx / BK, kk = idx % BK;
                const float4 v = *reinterpret_cast<const float4*>(
                    B + (size_t)row * DIN + k0 + kk);
                Bs[kk + 0][row] = v.x; Bs[kk + 1][row] = v.y;
                Bs[kk + 2][row] = v.z; Bs[kk + 3][row] = v.w;
            }
            __syncthreads();
#pragma unroll 4
            for (int kk = 0; kk < BK; ++kk) {
                float a[TM];
#pragma unroll
                for (int i = 0; i < TM; ++i) a[i] = As[kk][tm * TM + i];
#pragma unroll
                for (int q = 0; q < NQ; ++q) {
                    // lanes tn=0..15 read 16 consecutive float4s -> broadcast/2-way (free)
                    const float4 bv = *reinterpret_cast<const float4*>(
                        &Bs[kk][tn * 4 + 64 * q]);
#pragma unroll
                    for (int i = 0; i < TM; ++i) {
                        acc[i][q * 4 + 0] += a[i] * bv.x;
                        acc[i][q * 4 + 1] += a[i] * bv.y;
                        acc[i][q * 4 + 2] += a[i] * bv.z;
                        acc[i][q * 4 + 3] += a[i] * bv.w;
                    }
                }
            }
        }
    }
    // epilogue: bias (+relu), float4 stores
#pragma unroll
    for (int i = 0; i < TM; ++i) {
        const size_t t = (size_t)(m0 + tm * TM + i);
#pragma unroll
        for (int q = 0; q < NQ; ++q) {
            const int o = tn * 4 + 64 * q;
            float4 v;
            v.x = acc[i][q * 4 + 0] + bias[o + 0];
            v.y = acc[i][q * 4 + 1] + bias[o + 1];
            v.z = acc[i][q * 4 + 2] + bias[o + 2];
            v.w = acc[i][q * 4 + 3] + bias[o + 3];
            if (RELU) {
                v.x = fmaxf(v.x, 0.f); v.y = fmaxf(v.y, 0.f);
                v.z = fmaxf(v.z, 0.f); v.w = fmaxf(v.w, 0.f);
            }
            *reinterpret_cast<float4*>(out + t * BN + o) = v;
        }
    }
}

extern "C" void kernel_launch(void* const* d_in, const int* in_sizes, int n_in,
                              void* d_out, int out_size, void* d_ws, size_t ws_size,
                              hipStream_t stream) {
    const float* x     = (const float*)d_in[0];
    const int*   src0  = (const int*)d_in[1];
    const int*   src1  = (const int*)d_in[3];
    const int*   src2  = (const int*)d_in[5];
    const float* Wl0   = (const float*)d_in[7];
    const float* b0    = (const float*)d_in[8];
    const float* Wr0   = (const float*)d_in[9];
    const float* Wl1   = (const float*)d_in[10];
    const float* b1    = (const float*)d_in[11];
    const float* Wr1   = (const float*)d_in[12];
    const float* Wl2   = (const float*)d_in[13];
    const float* b2    = (const float*)d_in[14];
    const float* Wr2   = (const float*)d_in[15];
    float* out = (float*)d_out;

    // workspace layout (fp32)
    float* h1  = (float*)d_ws;                    // 102400 x 256
    float* h2  = h1 + (size_t)102400 * 256;       // 10240 x 256
    float* agg = h2 + (size_t)10240 * 256;        // up to 102400 x 128

    // ---- layer 0: din=128, dout=256, n_tgt=102400 ----
    agg_kernel<128><<<102400 / 8, 256, 0, stream>>>(x, src0, agg, 102400);
    sage_gemm<64, 256, 32, 128, true><<<102400 / 64, 256, 0, stream>>>(
        agg, x, Wl0, Wr0, b0, h1, 102400);

    // ---- layer 1: din=256, dout=256, n_tgt=10240 ----
    agg_kernel<256><<<10240 / 4, 256, 0, stream>>>(h1, src1, agg, 10240);
    sage_gemm<64, 256, 32, 256, true><<<10240 / 64, 256, 0, stream>>>(
        agg, h1, Wl1, Wr1, b1, h2, 10240);

    // ---- layer 2: din=256, dout=64, n_tgt=1024 ----
    agg_kernel<256><<<1024 / 4, 256, 0, stream>>>(h2, src2, agg, 1024);
    sage_gemm<16, 64, 32, 256, false><<<1024 / 16, 256, 0, stream>>>(
        agg, h2, Wl2, Wr2, b2, out, 1024);
}